// Round 4
// baseline (374.555 us; speedup 1.0000x reference)
//
#include <hip/hip_runtime.h>
#include <cstddef>

// Problem constants: N=64 state dim, L=16384 seq, BATCH=512, chunk m=128.
static constexpr int RCN = 512 * 128;   // 65536 (row, chunk) pairs

// ws layout (float offsets)
static constexpr size_t WS_W  = 0;       // W[r][i] = (Ab^r Bb)_i, 128x64 fp32
static constexpr size_t WS_G  = 8192;    // fused weights G, 192x128 fp32
static constexpr size_t WS_MD = 32768;   // M = Ab^128, 64x64 DOUBLE (8192 floats)
static constexpr size_t WS_BV = 40960;   // chunk vectors b, RCN x 64 fp32
static constexpr size_t WS_X  = WS_BV + (size_t)RCN * 64;  // chunk states X, RCN x 64 fp32

// ---------------------------------------------------------------------------
// In-place-capable 64x64x64 fp64 matmul on stride-65 LDS matrices.
// 256 threads. Thread t owns rows r4..r4+3 (r4 = (t>>4)*4) and the SWIZZLED
// column set {cl+16q, q=0..3} (cl = t&15): B-reads then spread over all 32
// banks (conflict-free) instead of 4-way aliasing; A-reads are 16-lane
// broadcasts. 8 LDS instr / 16 FMA, c-loop unrolled x4 for latency hiding.
// ACCUM_DEST: Dst += A*Bm (Dst may alias A); else Dst = A*Bm (may alias both).
// ---------------------------------------------------------------------------
template <bool ACCUM_DEST>
__device__ __forceinline__ void mm64(double* Dst, const double* A,
                                     const double* Bm, int t) {
  const int r4 = (t >> 4) << 2;
  const int cl = t & 15;
  double acc[4][4];
#pragma unroll
  for (int i = 0; i < 4; ++i)
#pragma unroll
    for (int q = 0; q < 4; ++q) acc[i][q] = 0.0;
#pragma unroll 4
  for (int c = 0; c < 64; ++c) {
    double a0 = A[(r4 + 0) * 65 + c];
    double a1 = A[(r4 + 1) * 65 + c];
    double a2 = A[(r4 + 2) * 65 + c];
    double a3 = A[(r4 + 3) * 65 + c];
    double b0 = Bm[c * 65 + cl];
    double b1 = Bm[c * 65 + cl + 16];
    double b2 = Bm[c * 65 + cl + 32];
    double b3 = Bm[c * 65 + cl + 48];
    acc[0][0] = fma(a0, b0, acc[0][0]); acc[0][1] = fma(a0, b1, acc[0][1]);
    acc[0][2] = fma(a0, b2, acc[0][2]); acc[0][3] = fma(a0, b3, acc[0][3]);
    acc[1][0] = fma(a1, b0, acc[1][0]); acc[1][1] = fma(a1, b1, acc[1][1]);
    acc[1][2] = fma(a1, b2, acc[1][2]); acc[1][3] = fma(a1, b3, acc[1][3]);
    acc[2][0] = fma(a2, b0, acc[2][0]); acc[2][1] = fma(a2, b1, acc[2][1]);
    acc[2][2] = fma(a2, b2, acc[2][2]); acc[2][3] = fma(a2, b3, acc[2][3]);
    acc[3][0] = fma(a3, b0, acc[3][0]); acc[3][1] = fma(a3, b1, acc[3][1]);
    acc[3][2] = fma(a3, b2, acc[3][2]); acc[3][3] = fma(a3, b3, acc[3][3]);
  }
  if (ACCUM_DEST) {
#pragma unroll
    for (int i = 0; i < 4; ++i)
#pragma unroll
      for (int q = 0; q < 4; ++q)
        acc[i][q] += Dst[(r4 + i) * 65 + cl + 16 * q];
  }
  __syncthreads();
#pragma unroll
  for (int i = 0; i < 4; ++i)
#pragma unroll
    for (int q = 0; q < 4; ++q)
      Dst[(r4 + i) * 65 + cl + 16 * q] = acc[i][q];
  __syncthreads();
}

// ---------------------------------------------------------------------------
// Kernel A: discretize + build all weights. 1 block x 256 threads.
//   fp64: N1 = inv(I-hA) via product-form Neumann (16 terms, 6 matmuls),
//   Ab = 2*N1 - I, M = Ab^128 (7 squarings) -> scan matrix.
//   fp32: W/H log-doubling sharing the squaring chain (powers <= 128 only,
//   amplification ~1.2x -> fp32 ample), reading fp32 shadow Pf of P.
// ---------------------------------------------------------------------------
__global__ __launch_bounds__(256) void k_precomp(
    const float* __restrict__ Ain, const float* __restrict__ Bin,
    const float* __restrict__ Cin, const float* __restrict__ Din,
    const float* __restrict__ LS, float* ws)
{
  __shared__ double Xd[64 * 65];   // hA, then hA^(2^k)
  __shared__ double Pd[64 * 65];   // Z -> N1 -> Ab -> P-chain -> M
  __shared__ float  Pf[64 * 65];   // fp32 shadow of Pd for W/H doubling
  __shared__ float  Wf[128 * 65];  // W[r][i]
  __shared__ float  Hf[128 * 65];  // H[r][i] = (C Ab^{r+1})_i
  __shared__ float  Kf[128];

  const int t = threadIdx.x;
  float*  Wg  = ws + WS_W;
  float*  Gg  = ws + WS_G;
  double* Mgd = (double*)(ws + WS_MD);

  const double step = exp((double)LS[0]);
  const double h = 0.5 * step;

  // X = h*A ; Z = I + X
  for (int idx = t; idx < 4096; idx += 256) {
    int i = idx >> 6, j = idx & 63;
    double a = h * (double)Ain[idx];
    Xd[i * 65 + j] = a;
    Pd[i * 65 + j] = a + ((i == j) ? 1.0 : 0.0);
  }
  __syncthreads();

  // Product-form Neumann: for k=0..2: X <- X^2 ; Z <- Z + Z*X
  // => Z = (I+X)(I+X^2)(I+X^4)(I+X^8) = sum_{j=0}^{15} X^j = N1.
  for (int k = 0; k < 3; ++k) {
    mm64<false>(Xd, Xd, Xd, t);
    mm64<true>(Pd, Pd, Xd, t);
  }

  // Bb = step * N1 @ B  -> W[0] (fp64 dot, 2-way row reads)
  if (t < 64) {
    double bb = 0.0;
    for (int c = 0; c < 64; ++c) bb = fma(Pd[t * 65 + c], (double)Bin[c], bb);
    Wf[t] = (float)(bb * step);
  }
  __syncthreads();  // all N1 reads complete before overwrite

  // Ab = 2*N1 - I (in place)
  for (int idx = t; idx < 4096; idx += 256) {
    int i = idx >> 6, j = idx & 63;
    Pd[i * 65 + j] = 2.0 * Pd[i * 65 + j] - ((i == j) ? 1.0 : 0.0);
  }
  __syncthreads();

  // H[0] = C @ Ab (fp64, column reads 2-way) ; Pf = fp32(Ab)
  if (t < 64) {
    double hh = 0.0;
    for (int c = 0; c < 64; ++c) hh = fma((double)Cin[c], Pd[c * 65 + t], hh);
    Hf[t] = (float)hh;
  }
  for (int idx = t; idx < 4096; idx += 256) {
    int i = idx >> 6, j = idx & 63;
    Pf[i * 65 + j] = (float)Pd[i * 65 + j];
  }
  __syncthreads();

  // Log-doubling: entry invariant P = Ab^n (n = 2^k), W[0..n), H[0..n) valid.
  //   W[n+r][i] = sum_c Pf[i][c]   * Wf[r][c]   (fp32)
  //   H[n+r][i] = sum_c Hf[r][c]   * Pf[c][i]   (fp32)
  //   P <- P*P (fp64, shared with M = Ab^128 chain); Pf refreshed.
  for (int k = 0; k < 7; ++k) {
    const int n = 1 << k;
    for (int o = t; o < (n << 6); o += 256) {
      int r = o >> 6, ii = o & 63;      // wave-uniform r, per-lane ii
      float aw = 0.f, ah = 0.f;
#pragma unroll 4
      for (int c = 0; c < 64; ++c) {
        aw = fmaf(Pf[ii * 65 + c], Wf[r * 65 + c], aw);
        ah = fmaf(Hf[r * 65 + c], Pf[c * 65 + ii], ah);
      }
      Wf[(n + r) * 65 + ii] = aw;
      Hf[(n + r) * 65 + ii] = ah;
    }
    __syncthreads();          // W/H writes done; Pd still = Ab^n everywhere
    mm64<false>(Pd, Pd, Pd, t);
    for (int idx = t; idx < 4096; idx += 256) {
      int i = idx >> 6, j = idx & 63;
      Pf[i * 65 + j] = (float)Pd[i * 65 + j];
    }
    __syncthreads();
  }
  // Pd = Ab^128 = M (fp64) -> global for k_scan
  for (int idx = t; idx < 4096; idx += 256)
    Mgd[idx] = Pd[(idx >> 6) * 65 + (idx & 63)];

  // K[r] = C . W[r]
  if (t < 128) {
    float s = 0.f;
#pragma unroll 4
    for (int c = 0; c < 64; ++c) s = fmaf(Cin[c], Wf[t * 65 + c], s);
    Kf[t] = s;
  }
  __syncthreads();

  // W -> global (dense 64-stride for k_chunkvec)
  for (int idx = t; idx < 8192; idx += 256)
    Wg[idx] = Wf[(idx >> 6) * 65 + (idx & 63)];

  // G Toeplitz part: G[k][r] = K[r-k] (r>=k) + D*(k==r)
  const float Dval = Din[0];
  for (int idx = t; idx < 16384; idx += 256) {
    int k = idx >> 7, r = idx & 127;
    float v = (r >= k) ? Kf[r - k] : 0.f;
    if (k == r) v += Dval;
    Gg[idx] = v;
  }
  // G cross-chunk part: G[128+i][r] = H[r][i]
  for (int idx = t; idx < 8192; idx += 256) {
    int i = idx >> 7, r = idx & 127;
    Gg[(128 + i) * 128 + r] = Hf[r * 65 + i];
  }
}

// ---------------------------------------------------------------------------
// Kernel B: chunk input vectors  b[rc][i] = sum_k u[rc][k] * W[127-k][i]
// GEMM M=65536, N=64, K=128. Block = 128 rc-rows, 128 threads, 8x8 tiles.
// ---------------------------------------------------------------------------
__global__ __launch_bounds__(128) void k_chunkvec(
    const float* __restrict__ u, const float* __restrict__ Wg,
    float* __restrict__ bout)
{
  __shared__ float As[32 * 132];  // [kk][rcl], transposed u slice
  __shared__ float Bs[32 * 68];   // [kk][i]
  const int t = threadIdx.x;
  const int rc0 = blockIdx.x << 7;
  const int trow = (t >> 3) << 3;
  const int tcol = (t & 7) << 3;
  float acc[8][8];
#pragma unroll
  for (int i = 0; i < 8; ++i)
#pragma unroll
    for (int j = 0; j < 8; ++j) acc[i][j] = 0.f;

  for (int sl = 0; sl < 4; ++sl) {
    for (int it = t; it < 1024; it += 128) {
      int rcl = it >> 3, k4 = (it & 7) << 2;
      float4 v = *(const float4*)&u[((size_t)(rc0 + rcl) << 7) + (sl << 5) + k4];
      As[(k4 + 0) * 132 + rcl] = v.x;
      As[(k4 + 1) * 132 + rcl] = v.y;
      As[(k4 + 2) * 132 + rcl] = v.z;
      As[(k4 + 3) * 132 + rcl] = v.w;
    }
    for (int it = t; it < 512; it += 128) {
      int kk = it >> 4, i4 = (it & 15) << 2;
      *(float4*)&Bs[kk * 68 + i4] =
          *(const float4*)&Wg[((size_t)(127 - ((sl << 5) + kk)) << 6) + i4];
    }
    __syncthreads();
#pragma unroll 4
    for (int kk = 0; kk < 32; ++kk) {
      float av[8], bv[8];
      *(float4*)&av[0] = *(const float4*)&As[kk * 132 + trow];
      *(float4*)&av[4] = *(const float4*)&As[kk * 132 + trow + 4];
      *(float4*)&bv[0] = *(const float4*)&Bs[kk * 68 + tcol];
      *(float4*)&bv[4] = *(const float4*)&Bs[kk * 68 + tcol + 4];
#pragma unroll
      for (int i = 0; i < 8; ++i)
#pragma unroll
        for (int j = 0; j < 8; ++j) acc[i][j] = fmaf(av[i], bv[j], acc[i][j]);
    }
    __syncthreads();
  }
#pragma unroll
  for (int i = 0; i < 8; ++i) {
    size_t base = ((size_t)(rc0 + trow + i) << 6) + tcol;
    *(float4*)&bout[base]     = make_float4(acc[i][0], acc[i][1], acc[i][2], acc[i][3]);
    *(float4*)&bout[base + 4] = make_float4(acc[i][4], acc[i][5], acc[i][6], acc[i][7]);
  }
}

// ---------------------------------------------------------------------------
// Kernel C: per-row chunk-state scan in fp64. X_0 = 0; X_{j+1} = M X_j + b_j.
// 256 threads/block: thread (i, q) covers M[i][16q..16q+16); partials reduced
// through LDS.
// ---------------------------------------------------------------------------
__global__ __launch_bounds__(256) void k_scan(
    const double* __restrict__ Mg, const float* __restrict__ bv,
    float* __restrict__ Xg)
{
  __shared__ double xs[64];
  __shared__ double part[3 * 64];
  const int t = threadIdx.x;
  const int i = t & 63, q = t >> 6;   // q is wave-uniform
  double Mr[16];
#pragma unroll
  for (int c = 0; c < 16; ++c) Mr[c] = Mg[((size_t)i << 6) + (q << 4) + c];
  const float* br = bv + ((size_t)blockIdx.x << 13);
  float* Xr = Xg + ((size_t)blockIdx.x << 13);
  if (t < 64) xs[t] = 0.0;
  __syncthreads();
  for (int j = 0; j < 128; ++j) {
    double s0 = 0, s1 = 0, s2 = 0, s3 = 0;
#pragma unroll
    for (int c = 0; c < 16; c += 4) {   // xs reads are wave-uniform broadcasts
      s0 = fma(Mr[c + 0], xs[(q << 4) + c + 0], s0);
      s1 = fma(Mr[c + 1], xs[(q << 4) + c + 1], s1);
      s2 = fma(Mr[c + 2], xs[(q << 4) + c + 2], s2);
      s3 = fma(Mr[c + 3], xs[(q << 4) + c + 3], s3);
    }
    double ps = (s0 + s1) + (s2 + s3);
    if (q) part[((q - 1) << 6) + i] = ps;
    __syncthreads();
    if (q == 0) {
      double xold = xs[i];
      Xr[(j << 6) + i] = (float)xold;                 // state at chunk start
      xs[i] = (double)br[(j << 6) + i] + ps + part[i] + part[64 + i] + part[128 + i];
    }
    __syncthreads();
  }
}

// ---------------------------------------------------------------------------
// Kernel D: main output GEMM. y[rc][r] = sum_{k<128} u[rc][k] G[k][r]
//                                       + sum_i X[rc][i] G[128+i][r]
// M=65536, N=128, K=192. Block = 128 rc-rows, 256 threads, 8x8 tiles.
// ---------------------------------------------------------------------------
__global__ __launch_bounds__(256) void k_main(
    const float* __restrict__ u, const float* __restrict__ Xg,
    const float* __restrict__ Gg, float* __restrict__ out)
{
  __shared__ float As[32 * 132];  // [kk][rcl]
  __shared__ float Bs[32 * 132];  // [kk][r]
  const int t = threadIdx.x;
  const int rc0 = blockIdx.x << 7;
  const int trow = (t >> 4) << 3;
  const int tcol = (t & 15) << 3;
  float acc[8][8];
#pragma unroll
  for (int i = 0; i < 8; ++i)
#pragma unroll
    for (int j = 0; j < 8; ++j) acc[i][j] = 0.f;

  for (int sl = 0; sl < 6; ++sl) {
    const int k0 = sl << 5;
    for (int it = t; it < 1024; it += 256) {
      int rcl = it >> 3, k4 = (it & 7) << 2;
      int kg = k0 + k4;
      float4 v;
      if (kg < 128)
        v = *(const float4*)&u[((size_t)(rc0 + rcl) << 7) + kg];
      else
        v = *(const float4*)&Xg[((size_t)(rc0 + rcl) << 6) + (kg - 128)];
      As[(k4 + 0) * 132 + rcl] = v.x;
      As[(k4 + 1) * 132 + rcl] = v.y;
      As[(k4 + 2) * 132 + rcl] = v.z;
      As[(k4 + 3) * 132 + rcl] = v.w;
    }
    for (int it = t; it < 1024; it += 256) {
      int kk = it >> 5, r4 = (it & 31) << 2;
      *(float4*)&Bs[kk * 132 + r4] = *(const float4*)&Gg[(size_t)(k0 + kk) * 128 + r4];
    }
    __syncthreads();
#pragma unroll 4
    for (int kk = 0; kk < 32; ++kk) {
      float av[8], bv[8];
      *(float4*)&av[0] = *(const float4*)&As[kk * 132 + trow];
      *(float4*)&av[4] = *(const float4*)&As[kk * 132 + trow + 4];
      *(float4*)&bv[0] = *(const float4*)&Bs[kk * 132 + tcol];
      *(float4*)&bv[4] = *(const float4*)&Bs[kk * 132 + tcol + 4];
#pragma unroll
      for (int i = 0; i < 8; ++i)
#pragma unroll
        for (int j = 0; j < 8; ++j) acc[i][j] = fmaf(av[i], bv[j], acc[i][j]);
    }
    __syncthreads();
  }
#pragma unroll
  for (int i = 0; i < 8; ++i) {
    size_t base = ((size_t)(rc0 + trow + i) << 7) + tcol;
    *(float4*)&out[base]     = make_float4(acc[i][0], acc[i][1], acc[i][2], acc[i][3]);
    *(float4*)&out[base + 4] = make_float4(acc[i][4], acc[i][5], acc[i][6], acc[i][7]);
  }
}

// ---------------------------------------------------------------------------
extern "C" void kernel_launch(void* const* d_in, const int* in_sizes, int n_in,
                              void* d_out, int out_size, void* d_ws, size_t ws_size,
                              hipStream_t stream) {
  (void)in_sizes; (void)n_in; (void)out_size; (void)ws_size;
  const float* u  = (const float*)d_in[0];
  const float* A  = (const float*)d_in[1];
  const float* Bv = (const float*)d_in[2];
  const float* Cv = (const float*)d_in[3];
  const float* Dv = (const float*)d_in[4];
  const float* ls = (const float*)d_in[5];
  float* out = (float*)d_out;
  float* ws  = (float*)d_ws;

  k_precomp<<<1, 256, 0, stream>>>(A, Bv, Cv, Dv, ls, ws);
  k_chunkvec<<<512, 128, 0, stream>>>(u, ws + WS_W, ws + WS_BV);
  k_scan<<<512, 256, 0, stream>>>((const double*)(ws + WS_MD), ws + WS_BV, ws + WS_X);
  k_main<<<512, 256, 0, stream>>>(u, ws + WS_X, ws + WS_G, out);
}